// Round 13
// baseline (204.384 us; speedup 1.0000x reference)
//
#include <hip/hip_runtime.h>

#define NN 50000
#define NE 1600000
#define D 64
#define NR 6
#define NSEG (NN * NR)          // 300000
#define KTOT 448                // 7 * 64  (6 relations + root slot)
#define SB 512
#define SNB ((NSEG + SB - 1) / SB)   // 586
#define BFRAG_N (4 * 14 * 64 * 8)    // 28672
#define NTH16 (NE / 16)         // 100000
#define NTH8  (NE / 8)          // 200000

typedef __attribute__((ext_vector_type(8))) short short8;
typedef __attribute__((ext_vector_type(4))) float f32x4;

__device__ __forceinline__ unsigned short f2bf(float f) {
    unsigned int u = __float_as_uint(f);
    unsigned int r = (u + 0x7FFF + ((u >> 16) & 1)) >> 16;   // RNE
    return (unsigned short)r;
}
__device__ __forceinline__ float bf2f(unsigned int h) {
    return __uint_as_float(h << 16);
}

// fused prep: zero cnt, x->bf16 (xh), A slot-6 (= xh row), Bfrag build
__global__ void prep_k(const float* __restrict__ x, const float* __restrict__ W,
                       const float* __restrict__ root, int* __restrict__ cnt,
                       unsigned short* __restrict__ xh, unsigned short* __restrict__ A,
                       unsigned short* __restrict__ Bfrag) {
    int t = blockIdx.x * blockDim.x + threadIdx.x;
    if (t < NN * D) {
        unsigned short h = f2bf(x[t]);
        xh[t] = h;
        A[(size_t)(t >> 6) * KTOT + 6 * 64 + (t & 63)] = h;
    }
    if (t < NSEG) cnt[t] = 0;
    if (t < BFRAG_N) {
        int j = t & 7;
        int lane = (t >> 3) & 63;
        int rest = t >> 9;
        int ks = rest % 14;
        int nt = rest / 14;
        int k = ks * 32 + ((lane >> 4) * 8) + j;
        int n = nt * 16 + (lane & 15);
        float v = (k < 384) ? W[(size_t)k * 64 + n] : root[(size_t)(k - 384) * 64 + n];
        Bfrag[t] = f2bf(v);
    }
}

// rank assignment: 16 edges per thread, 16 independent atomics in flight
__global__ void count_rank_k(const int* __restrict__ dsts, const int* __restrict__ et,
                             int* __restrict__ cnt, int* __restrict__ rank) {
    int t = blockIdx.x * blockDim.x + threadIdx.x;
    if (t >= NTH16) return;
#pragma unroll
    for (int j = 0; j < 16; ++j) {
        int e = t + j * NTH16;
        int seg = dsts[e] * NR + et[e];
        rank[e] = atomicAdd(&cnt[seg], 1);
    }
}

// ---- two-level exclusive scan over cnt[NSEG] -> rowstart[NSEG+1] ----
__global__ void scanA_k(const int* __restrict__ cnt, int* __restrict__ incl,
                        int* __restrict__ blocksum) {
    __shared__ int s[SB];
    int t = threadIdx.x, i = blockIdx.x * SB + t;
    s[t] = (i < NSEG) ? cnt[i] : 0;
    __syncthreads();
    for (int off = 1; off < SB; off <<= 1) {
        int u = (t >= off) ? s[t - off] : 0;
        __syncthreads();
        s[t] += u;
        __syncthreads();
    }
    if (i < NSEG) incl[i] = s[t];
    if (t == SB - 1) blocksum[blockIdx.x] = s[t];
}

__global__ void scanB_k(const int* __restrict__ blocksum, int* __restrict__ blockoff) {
    __shared__ int s[1024];
    int t = threadIdx.x;
    s[t] = (t < SNB) ? blocksum[t] : 0;
    __syncthreads();
    for (int off = 1; off < 1024; off <<= 1) {
        int u = (t >= off) ? s[t - off] : 0;
        __syncthreads();
        s[t] += u;
        __syncthreads();
    }
    if (t < SNB) blockoff[t] = s[t];
}

__global__ void scanC_k(const int* __restrict__ incl, const int* __restrict__ blockoff,
                        int* __restrict__ rowstart) {
    int i = blockIdx.x * blockDim.x + threadIdx.x;
    if (i >= NSEG) return;
    int b = i / SB;
    int Ri = incl[i] + (b > 0 ? blockoff[b - 1] : 0);
    rowstart[i + 1] = Ri;
    if (i == 0) rowstart[0] = 0;
}

// placement: no atomics; pos = rowstart[seg] + rank[e]; 8 edges/thread.
// pay holds PRE-SHIFTED byte offsets (src*128) for agg's gather.
__global__ void place_k(const int* __restrict__ srcs, const int* __restrict__ dsts,
                        const int* __restrict__ et, const int* __restrict__ rowstart,
                        const int* __restrict__ rank, int* __restrict__ pay) {
    int t = blockIdx.x * blockDim.x + threadIdx.x;
    if (t >= NTH8) return;
#pragma unroll
    for (int j = 0; j < 8; ++j) {
        int e = t + j * NTH8;
        int seg = dsts[e] * NR + et[e];
        pay[rowstart[seg] + rank[e]] = srcs[e] << 7;
    }
}

// One wave per segment; 4 edges per gather instruction.
// lane: q = lane&15 (channel quad -> channels {4q..4q+3}), p = lane>>4 (edge slot).
__global__ __launch_bounds__(256) void agg7_k(const unsigned short* __restrict__ xh,
                                              const int* __restrict__ rowstart,
                                              const int* __restrict__ pay,
                                              unsigned short* __restrict__ A) {
    int n = (blockIdx.x * blockDim.x + threadIdx.x) >> 6;   // node index
    if (n >= NN) return;
    int r = blockIdx.y;                                     // relation
    int wid = n * NR + r;
    int lane = threadIdx.x & 63;
    int q = lane & 15;
    int p = lane >> 4;
    int k0 = rowstart[wid], k1 = rowstart[wid + 1];
    const char* xb = (const char*)xh;
    unsigned int qo = (unsigned int)q << 3;                 // byte offset within row
    float a0 = 0.f, a1 = 0.f, a2 = 0.f, a3 = 0.f;
    int k = k0;
    for (; k + 8 <= k1; k += 8) {
        unsigned int pv0 = (unsigned int)pay[k + p];
        unsigned int pv1 = (unsigned int)pay[k + 4 + p];
        uint2 u0 = *(const uint2*)(xb + pv0 + qo);
        uint2 u1 = *(const uint2*)(xb + pv1 + qo);
        a0 += bf2f(u0.x & 0xFFFFu) + bf2f(u1.x & 0xFFFFu);
        a1 += bf2f(u0.x >> 16)     + bf2f(u1.x >> 16);
        a2 += bf2f(u0.y & 0xFFFFu) + bf2f(u1.y & 0xFFFFu);
        a3 += bf2f(u0.y >> 16)     + bf2f(u1.y >> 16);
    }
    if (k < k1) {                       // masked tail: up to 7 edges
        int kk0 = k + p;
        int kk1 = k + 4 + p;
        bool v0 = kk0 < k1, v1 = kk1 < k1;
        float m0 = v0 ? 1.0f : 0.0f, m1 = v1 ? 1.0f : 0.0f;
        unsigned int pv0 = (unsigned int)pay[v0 ? kk0 : k];
        unsigned int pv1 = (unsigned int)pay[v1 ? kk1 : k];
        uint2 u0 = *(const uint2*)(xb + pv0 + qo);
        uint2 u1 = *(const uint2*)(xb + pv1 + qo);
        a0 += bf2f(u0.x & 0xFFFFu) * m0 + bf2f(u1.x & 0xFFFFu) * m1;
        a1 += bf2f(u0.x >> 16) * m0     + bf2f(u1.x >> 16) * m1;
        a2 += bf2f(u0.y & 0xFFFFu) * m0 + bf2f(u1.y & 0xFFFFu) * m1;
        a3 += bf2f(u0.y >> 16) * m0     + bf2f(u1.y >> 16) * m1;
    }
    a0 += __shfl_down(a0, 16); a0 += __shfl_down(a0, 32);
    a1 += __shfl_down(a1, 16); a1 += __shfl_down(a1, 32);
    a2 += __shfl_down(a2, 16); a2 += __shfl_down(a2, 32);
    a3 += __shfl_down(a3, 16); a3 += __shfl_down(a3, 32);
    if (p == 0) {
        int c = k1 - k0;
        float nrm = (c > 0) ? 1.0f / (float)c : 0.0f;
        uint2 o;
        o.x = (unsigned int)f2bf(a0 * nrm) | ((unsigned int)f2bf(a1 * nrm) << 16);
        o.y = (unsigned int)f2bf(a2 * nrm) | ((unsigned int)f2bf(a3 * nrm) << 16);
        *(uint2*)(A + (size_t)n * KTOT + r * 64 + 4 * q) = o;
    }
}

// MFMA GEMM: out = bias + A @ B; M=NN, K=448, N=64. 4 waves/block, 16-row strips.
__global__ __launch_bounds__(256) void mix3_k(const unsigned short* __restrict__ A,
                                              const unsigned short* __restrict__ Bfrag,
                                              const float* __restrict__ bias,
                                              float* __restrict__ out) {
    int t = threadIdx.x;
    int lane = t & 63;
    int w = t >> 6;
    int rowb = blockIdx.x * 64 + w * 16;
    int arow = rowb + (lane & 15);
    if (arow >= NN) arow = NN - 1;
    const short8* ap = (const short8*)(A + (size_t)arow * KTOT + ((lane >> 4) * 8));
    const short8* bp = (const short8*)Bfrag + lane;
    f32x4 acc0 = {0.f, 0.f, 0.f, 0.f};
    f32x4 acc1 = acc0, acc2 = acc0, acc3 = acc0;
#pragma unroll
    for (int ks = 0; ks < 14; ++ks) {
        short8 a = ap[ks * 4];
        short8 b0 = bp[(0 * 14 + ks) * 64];
        short8 b1 = bp[(1 * 14 + ks) * 64];
        short8 b2 = bp[(2 * 14 + ks) * 64];
        short8 b3 = bp[(3 * 14 + ks) * 64];
        acc0 = __builtin_amdgcn_mfma_f32_16x16x32_bf16(a, b0, acc0, 0, 0, 0);
        acc1 = __builtin_amdgcn_mfma_f32_16x16x32_bf16(a, b1, acc1, 0, 0, 0);
        acc2 = __builtin_amdgcn_mfma_f32_16x16x32_bf16(a, b2, acc2, 0, 0, 0);
        acc3 = __builtin_amdgcn_mfma_f32_16x16x32_bf16(a, b3, acc3, 0, 0, 0);
    }
    int col = lane & 15;
    int rout = rowb + (lane >> 4) * 4;
    float bv0 = bias[0 * 16 + col];
    float bv1 = bias[1 * 16 + col];
    float bv2 = bias[2 * 16 + col];
    float bv3 = bias[3 * 16 + col];
#pragma unroll
    for (int j = 0; j < 4; ++j) {
        int rr = rout + j;
        if (rr < NN) {
            float* op = out + (size_t)rr * 64;
            op[0 * 16 + col] = acc0[j] + bv0;
            op[1 * 16 + col] = acc1[j] + bv1;
            op[2 * 16 + col] = acc2[j] + bv2;
            op[3 * 16 + col] = acc3[j] + bv3;
        }
    }
}

// ---------- fallback path (small ws) ----------
__global__ void zero_i32_k(int* __restrict__ p, int n) {
    int i = blockIdx.x * blockDim.x + threadIdx.x;
    if (i < n) p[i] = 0;
}

__global__ void count_edges_k(const int* __restrict__ dst, const int* __restrict__ et,
                              int* __restrict__ cnt) {
    int e = blockIdx.x * blockDim.x + threadIdx.x;
    if (e < NE) atomicAdd(&cnt[dst[e] * NR + et[e]], 1);
}

__global__ void make_norm_k(const int* __restrict__ cnt, float* __restrict__ norm, int n) {
    int i = blockIdx.x * blockDim.x + threadIdx.x;
    if (i < n) {
        int c = cnt[i];
        norm[i] = (c > 0) ? 1.0f / (float)c : 0.0f;
    }
}

__global__ void init_out_k(const float* __restrict__ x, const float* __restrict__ root,
                           const float* __restrict__ bias, float* __restrict__ out) {
    int t = blockIdx.x * blockDim.x + threadIdx.x;
    int n = t >> 6;
    int o = t & 63;
    if (n >= NN) return;
    const float* xrow = x + n * D;
    float acc = bias[o];
#pragma unroll
    for (int d = 0; d < D; ++d) acc = fmaf(xrow[d], root[d * D + o], acc);
    out[t] = acc;
}

__global__ void scatter_mv_k(const int* __restrict__ srcs, const int* __restrict__ dsts,
                             const int* __restrict__ et, const float* __restrict__ x,
                             const float* __restrict__ W, const float* __restrict__ norm,
                             float* __restrict__ out) {
    int t = blockIdx.x * blockDim.x + threadIdx.x;
    int e = t >> 6;
    int o = t & 63;
    if (e >= NE) return;
    int s = srcs[e];
    int d2 = dsts[e];
    int r = et[e];
    float nrm = norm[d2 * NR + r];
    const float* xrow = x + s * D;
    const float* Wr = W + r * D * D + o;
    float acc = 0.0f;
#pragma unroll
    for (int d = 0; d < D; ++d) acc = fmaf(xrow[d], Wr[d * D], acc);
    atomicAdd(&out[d2 * D + o], acc * nrm);
}

extern "C" void kernel_launch(void* const* d_in, const int* in_sizes, int n_in,
                              void* d_out, int out_size, void* d_ws, size_t ws_size,
                              hipStream_t stream) {
    const float* x    = (const float*)d_in[0];
    const float* W    = (const float*)d_in[1];
    const float* root = (const float*)d_in[2];
    const float* bias = (const float*)d_in[3];
    const int*   ei   = (const int*)d_in[4];
    const int*   et   = (const int*)d_in[5];
    float* out = (float*)d_out;
    const int* srcs = ei;
    const int* dsts = ei + NE;

    // fully disjoint workspace layout (~70 MB)
    char* ws = (char*)d_ws;
    size_t off = 0;
    int*   rowstart = (int*)(ws + off); off += (size_t)(NSEG + 1) * 4;
    int*   pay      = (int*)(ws + off); off += (size_t)NE * 4;
    int*   rank     = (int*)(ws + off); off += (size_t)NE * 4;
    off = (off + 255) & ~(size_t)255;
    unsigned short* Bfrag = (unsigned short*)(ws + off); off += (size_t)BFRAG_N * 2;
    off = (off + 255) & ~(size_t)255;
    unsigned short* xh = (unsigned short*)(ws + off); off += (size_t)NN * D * 2;
    off = (off + 255) & ~(size_t)255;
    int* cnt      = (int*)(ws + off); off += (size_t)NSEG * 4;
    int* incl     = (int*)(ws + off); off += (size_t)NSEG * 4;
    int* blocksum = (int*)(ws + off); off += (size_t)SNB * 4;
    int* blockoff = (int*)(ws + off); off += (size_t)SNB * 4;
    off = (off + 255) & ~(size_t)255;
    unsigned short* A = (unsigned short*)(ws + off); off += (size_t)NN * KTOT * 2;
    bool big = ws_size >= off;

    if (big) {
        prep_k<<<(NN * D + 255) / 256, 256, 0, stream>>>(x, W, root, cnt, xh, A, Bfrag);
        count_rank_k<<<(NTH16 + 255) / 256, 256, 0, stream>>>(dsts, et, cnt, rank);
        scanA_k<<<SNB, SB, 0, stream>>>(cnt, incl, blocksum);
        scanB_k<<<1, 1024, 0, stream>>>(blocksum, blockoff);
        scanC_k<<<(NSEG + 255) / 256, 256, 0, stream>>>(incl, blockoff, rowstart);
        place_k<<<(NTH8 + 255) / 256, 256, 0, stream>>>(srcs, dsts, et, rowstart, rank, pay);
        dim3 agrid((NN * 64 + 255) / 256, NR);
        agg7_k<<<agrid, 256, 0, stream>>>(xh, rowstart, pay, A);
        mix3_k<<<(NN + 63) / 64, 256, 0, stream>>>(A, Bfrag, bias, out);
    } else {
        int* cnt2  = (int*)(ws);
        float* norm = (float*)(ws + (size_t)NSEG * 4);
        zero_i32_k<<<(NSEG + 255) / 256, 256, 0, stream>>>(cnt2, NSEG);
        count_edges_k<<<(NE + 255) / 256, 256, 0, stream>>>(dsts, et, cnt2);
        make_norm_k<<<(NSEG + 255) / 256, 256, 0, stream>>>(cnt2, norm, NSEG);
        init_out_k<<<((size_t)NN * 64 + 255) / 256, 256, 0, stream>>>(x, root, bias, out);
        scatter_mv_k<<<((size_t)NE * 64 + 255) / 256, 256, 0, stream>>>(srcs, dsts, et, x, W, norm, out);
    }
}

// Round 14
// 182.073 us; speedup vs baseline: 1.1225x; 1.1225x over previous
//
#include <hip/hip_runtime.h>

#define NN 50000
#define NE 1600000
#define D 64
#define NR 6
#define NSEG (NN * NR)          // 300000
#define SB 512
#define SNB ((NSEG + SB - 1) / SB)   // 586
#define BFRAG_N (4 * 14 * 64 * 8)    // 28672
#define NTH16 (NE / 16)         // 100000
#define NTH8  (NE / 8)          // 200000

typedef __attribute__((ext_vector_type(8))) short short8;
typedef __attribute__((ext_vector_type(4))) float f32x4;

__device__ __forceinline__ unsigned short f2bf(float f) {
    unsigned int u = __float_as_uint(f);
    unsigned int r = (u + 0x7FFF + ((u >> 16) & 1)) >> 16;   // RNE
    return (unsigned short)r;
}

// fused prep: zero cnt, x->bf16 (xh), Bfrag build
__global__ void prep_k(const float* __restrict__ x, const float* __restrict__ W,
                       const float* __restrict__ root, int* __restrict__ cnt,
                       unsigned short* __restrict__ xh, unsigned short* __restrict__ Bfrag) {
    int t = blockIdx.x * blockDim.x + threadIdx.x;
    if (t < NN * D) xh[t] = f2bf(x[t]);
    if (t < NSEG) cnt[t] = 0;
    if (t < BFRAG_N) {
        int j = t & 7;
        int lane = (t >> 3) & 63;
        int rest = t >> 9;
        int ks = rest % 14;
        int nt = rest / 14;
        int k = ks * 32 + ((lane >> 4) * 8) + j;
        int n = nt * 16 + (lane & 15);
        float v = (k < 384) ? W[(size_t)k * 64 + n] : root[(size_t)(k - 384) * 64 + n];
        Bfrag[t] = f2bf(v);
    }
}

// rank assignment: 16 edges per thread, 16 independent atomics in flight
__global__ void count_rank_k(const int* __restrict__ dsts, const int* __restrict__ et,
                             int* __restrict__ cnt, int* __restrict__ rank) {
    int t = blockIdx.x * blockDim.x + threadIdx.x;
    if (t >= NTH16) return;
#pragma unroll
    for (int j = 0; j < 16; ++j) {
        int e = t + j * NTH16;
        int seg = dsts[e] * NR + et[e];
        rank[e] = atomicAdd(&cnt[seg], 1);
    }
}

// ---- two-level exclusive scan over cnt[NSEG] -> rowstart[NSEG+1] ----
__global__ void scanA_k(const int* __restrict__ cnt, int* __restrict__ incl,
                        int* __restrict__ blocksum) {
    __shared__ int s[SB];
    int t = threadIdx.x, i = blockIdx.x * SB + t;
    s[t] = (i < NSEG) ? cnt[i] : 0;
    __syncthreads();
    for (int off = 1; off < SB; off <<= 1) {
        int u = (t >= off) ? s[t - off] : 0;
        __syncthreads();
        s[t] += u;
        __syncthreads();
    }
    if (i < NSEG) incl[i] = s[t];
    if (t == SB - 1) blocksum[blockIdx.x] = s[t];
}

__global__ void scanB_k(const int* __restrict__ blocksum, int* __restrict__ blockoff) {
    __shared__ int s[1024];
    int t = threadIdx.x;
    s[t] = (t < SNB) ? blocksum[t] : 0;
    __syncthreads();
    for (int off = 1; off < 1024; off <<= 1) {
        int u = (t >= off) ? s[t - off] : 0;
        __syncthreads();
        s[t] += u;
        __syncthreads();
    }
    if (t < SNB) blockoff[t] = s[t];
}

__global__ void scanC_k(const int* __restrict__ incl, const int* __restrict__ blockoff,
                        int* __restrict__ rowstart) {
    int i = blockIdx.x * blockDim.x + threadIdx.x;
    if (i >= NSEG) return;
    int b = i / SB;
    int Ri = incl[i] + (b > 0 ? blockoff[b - 1] : 0);
    rowstart[i + 1] = Ri;
    if (i == 0) rowstart[0] = 0;
}

// placement: no atomics; pos = rowstart[seg] + rank[e]; 8 edges/thread.
// pay holds PRE-SHIFTED byte offsets (src*128) for agg's gather.
__global__ void place_k(const int* __restrict__ srcs, const int* __restrict__ dsts,
                        const int* __restrict__ et, const int* __restrict__ rowstart,
                        const int* __restrict__ rank, int* __restrict__ pay) {
    int t = blockIdx.x * blockDim.x + threadIdx.x;
    if (t >= NTH8) return;
#pragma unroll
    for (int j = 0; j < 8; ++j) {
        int e = t + j * NTH8;
        int seg = dsts[e] * NR + et[e];
        pay[rowstart[seg] + rank[e]] = srcs[e] << 7;
    }
}

// Two segments per wave: lane group g=lane>>5 owns segment 2*wave+g;
// cp=lane&31 owns channels {2cp,2cp+1}. No shfl, no division.
// Amain offset = seg*64 (seg-major = [n][r*64+d] for KTOT=384).
__global__ __launch_bounds__(256) void agg8_k(const unsigned short* __restrict__ xh,
                                              const int* __restrict__ rowstart,
                                              const int* __restrict__ pay,
                                              unsigned short* __restrict__ Amain) {
    int wv = (blockIdx.x * blockDim.x + threadIdx.x) >> 6;
    int lane = threadIdx.x & 63;
    int g = lane >> 5;
    int cp = lane & 31;
    int seg = 2 * wv + g;
    if (seg >= NSEG) return;
    int k0 = rowstart[seg], k1 = rowstart[seg + 1];
    const char* xb = (const char*)xh;
    unsigned int cpo = (unsigned int)cp << 2;               // byte offset within row
    float ax = 0.f, ay = 0.f;
    for (int k = k0; k < k1; k += 4) {
        unsigned int pv[4];
        float mv[4];
#pragma unroll
        for (int j = 0; j < 4; ++j) {
            int kk = k + j;
            bool v = kk < k1;
            mv[j] = v ? 1.0f : 0.0f;
            pv[j] = (unsigned int)pay[v ? kk : k];          // k < k1 <= NE, always valid
        }
#pragma unroll
        for (int j = 0; j < 4; ++j) {
            unsigned int u = *(const unsigned int*)(xb + pv[j] + cpo);
            ax += __uint_as_float(u << 16) * mv[j];          // channel 2cp
            ay += __uint_as_float(u & 0xFFFF0000u) * mv[j];  // channel 2cp+1
        }
    }
    int c = k1 - k0;
    float nrm = (c > 0) ? 1.0f / (float)c : 0.0f;
    unsigned int o = (unsigned int)f2bf(ax * nrm) | ((unsigned int)f2bf(ay * nrm) << 16);
    *(unsigned int*)(Amain + (size_t)seg * 64 + 2 * cp) = o;
}

// MFMA GEMM: out = bias + A @ B; M=NN, K=448, N=64. K slots 0-383 from Amain,
// 384-447 (root term) straight from xh. 4 waves/block, 16-row strips.
__global__ __launch_bounds__(256) void mix4_k(const unsigned short* __restrict__ Amain,
                                              const unsigned short* __restrict__ xh,
                                              const unsigned short* __restrict__ Bfrag,
                                              const float* __restrict__ bias,
                                              float* __restrict__ out) {
    int t = threadIdx.x;
    int lane = t & 63;
    int w = t >> 6;
    int rowb = blockIdx.x * 64 + w * 16;
    int arow = rowb + (lane & 15);
    if (arow >= NN) arow = NN - 1;
    int ko = (lane >> 4) * 8;
    const unsigned short* ap = Amain + (size_t)arow * 384 + ko;
    const unsigned short* xp = xh + (size_t)arow * 64 + ko;
    const short8* bp = (const short8*)Bfrag + lane;
    f32x4 acc0 = {0.f, 0.f, 0.f, 0.f};
    f32x4 acc1 = acc0, acc2 = acc0, acc3 = acc0;
#pragma unroll
    for (int ks = 0; ks < 14; ++ks) {
        short8 a = (ks < 12) ? *(const short8*)(ap + ks * 32)
                             : *(const short8*)(xp + (ks - 12) * 32);
        short8 b0 = bp[(0 * 14 + ks) * 64];
        short8 b1 = bp[(1 * 14 + ks) * 64];
        short8 b2 = bp[(2 * 14 + ks) * 64];
        short8 b3 = bp[(3 * 14 + ks) * 64];
        acc0 = __builtin_amdgcn_mfma_f32_16x16x32_bf16(a, b0, acc0, 0, 0, 0);
        acc1 = __builtin_amdgcn_mfma_f32_16x16x32_bf16(a, b1, acc1, 0, 0, 0);
        acc2 = __builtin_amdgcn_mfma_f32_16x16x32_bf16(a, b2, acc2, 0, 0, 0);
        acc3 = __builtin_amdgcn_mfma_f32_16x16x32_bf16(a, b3, acc3, 0, 0, 0);
    }
    int col = lane & 15;
    int rout = rowb + (lane >> 4) * 4;
    float bv0 = bias[0 * 16 + col];
    float bv1 = bias[1 * 16 + col];
    float bv2 = bias[2 * 16 + col];
    float bv3 = bias[3 * 16 + col];
#pragma unroll
    for (int j = 0; j < 4; ++j) {
        int rr = rout + j;
        if (rr < NN) {
            float* op = out + (size_t)rr * 64;
            op[0 * 16 + col] = acc0[j] + bv0;
            op[1 * 16 + col] = acc1[j] + bv1;
            op[2 * 16 + col] = acc2[j] + bv2;
            op[3 * 16 + col] = acc3[j] + bv3;
        }
    }
}

// ---------- fallback path (small ws) ----------
__global__ void zero_i32_k(int* __restrict__ p, int n) {
    int i = blockIdx.x * blockDim.x + threadIdx.x;
    if (i < n) p[i] = 0;
}

__global__ void count_edges_k(const int* __restrict__ dst, const int* __restrict__ et,
                              int* __restrict__ cnt) {
    int e = blockIdx.x * blockDim.x + threadIdx.x;
    if (e < NE) atomicAdd(&cnt[dst[e] * NR + et[e]], 1);
}

__global__ void make_norm_k(const int* __restrict__ cnt, float* __restrict__ norm, int n) {
    int i = blockIdx.x * blockDim.x + threadIdx.x;
    if (i < n) {
        int c = cnt[i];
        norm[i] = (c > 0) ? 1.0f / (float)c : 0.0f;
    }
}

__global__ void init_out_k(const float* __restrict__ x, const float* __restrict__ root,
                           const float* __restrict__ bias, float* __restrict__ out) {
    int t = blockIdx.x * blockDim.x + threadIdx.x;
    int n = t >> 6;
    int o = t & 63;
    if (n >= NN) return;
    const float* xrow = x + n * D;
    float acc = bias[o];
#pragma unroll
    for (int d = 0; d < D; ++d) acc = fmaf(xrow[d], root[d * D + o], acc);
    out[t] = acc;
}

__global__ void scatter_mv_k(const int* __restrict__ srcs, const int* __restrict__ dsts,
                             const int* __restrict__ et, const float* __restrict__ x,
                             const float* __restrict__ W, const float* __restrict__ norm,
                             float* __restrict__ out) {
    int t = blockIdx.x * blockDim.x + threadIdx.x;
    int e = t >> 6;
    int o = t & 63;
    if (e >= NE) return;
    int s = srcs[e];
    int d2 = dsts[e];
    int r = et[e];
    float nrm = norm[d2 * NR + r];
    const float* xrow = x + s * D;
    const float* Wr = W + r * D * D + o;
    float acc = 0.0f;
#pragma unroll
    for (int d = 0; d < D; ++d) acc = fmaf(xrow[d], Wr[d * D], acc);
    atomicAdd(&out[d2 * D + o], acc * nrm);
}

extern "C" void kernel_launch(void* const* d_in, const int* in_sizes, int n_in,
                              void* d_out, int out_size, void* d_ws, size_t ws_size,
                              hipStream_t stream) {
    const float* x    = (const float*)d_in[0];
    const float* W    = (const float*)d_in[1];
    const float* root = (const float*)d_in[2];
    const float* bias = (const float*)d_in[3];
    const int*   ei   = (const int*)d_in[4];
    const int*   et   = (const int*)d_in[5];
    float* out = (float*)d_out;
    const int* srcs = ei;
    const int* dsts = ei + NE;

    // fully disjoint workspace layout (~64 MB)
    char* ws = (char*)d_ws;
    size_t off = 0;
    int*   rowstart = (int*)(ws + off); off += (size_t)(NSEG + 1) * 4;
    int*   pay      = (int*)(ws + off); off += (size_t)NE * 4;
    int*   rank     = (int*)(ws + off); off += (size_t)NE * 4;
    off = (off + 255) & ~(size_t)255;
    unsigned short* Bfrag = (unsigned short*)(ws + off); off += (size_t)BFRAG_N * 2;
    off = (off + 255) & ~(size_t)255;
    unsigned short* xh = (unsigned short*)(ws + off); off += (size_t)NN * D * 2;
    off = (off + 255) & ~(size_t)255;
    int* cnt      = (int*)(ws + off); off += (size_t)NSEG * 4;
    int* incl     = (int*)(ws + off); off += (size_t)NSEG * 4;
    int* blocksum = (int*)(ws + off); off += (size_t)SNB * 4;
    int* blockoff = (int*)(ws + off); off += (size_t)SNB * 4;
    off = (off + 255) & ~(size_t)255;
    unsigned short* Amain = (unsigned short*)(ws + off); off += (size_t)NN * 384 * 2;  // 38.4 MB
    bool big = ws_size >= off;

    if (big) {
        prep_k<<<(NN * D + 255) / 256, 256, 0, stream>>>(x, W, root, cnt, xh, Bfrag);
        count_rank_k<<<(NTH16 + 255) / 256, 256, 0, stream>>>(dsts, et, cnt, rank);
        scanA_k<<<SNB, SB, 0, stream>>>(cnt, incl, blocksum);
        scanB_k<<<1, 1024, 0, stream>>>(blocksum, blockoff);
        scanC_k<<<(NSEG + 255) / 256, 256, 0, stream>>>(incl, blockoff, rowstart);
        place_k<<<(NTH8 + 255) / 256, 256, 0, stream>>>(srcs, dsts, et, rowstart, rank, pay);
        int aggwaves = NSEG / 2;                      // 150000
        agg8_k<<<((size_t)aggwaves * 64 + 255) / 256, 256, 0, stream>>>(xh, rowstart, pay, Amain);
        mix4_k<<<(NN + 63) / 64, 256, 0, stream>>>(Amain, xh, Bfrag, bias, out);
    } else {
        int* cnt2  = (int*)(ws);
        float* norm = (float*)(ws + (size_t)NSEG * 4);
        zero_i32_k<<<(NSEG + 255) / 256, 256, 0, stream>>>(cnt2, NSEG);
        count_edges_k<<<(NE + 255) / 256, 256, 0, stream>>>(dsts, et, cnt2);
        make_norm_k<<<(NSEG + 255) / 256, 256, 0, stream>>>(cnt2, norm, NSEG);
        init_out_k<<<((size_t)NN * 64 + 255) / 256, 256, 0, stream>>>(x, root, bias, out);
        scatter_mv_k<<<((size_t)NE * 64 + 255) / 256, 256, 0, stream>>>(srcs, dsts, et, x, W, norm, out);
    }
}